// Round 1
// baseline (1240.797 us; speedup 1.0000x reference)
//
#include <hip/hip_runtime.h>
#include <math.h>

// Problem constants
#define BB    2
#define SS    384
#define DD    128
#define NH    8
#define HDIM  16
#define NBH   16      // B*H
#define BS    768     // B*S

// ---------------- compile-time Cl(4,1) geometric-product sign table ----------
struct SignTab { float v[32][32]; };

constexpr int popcnt32c(int x){ int c=0; for(int i=0;i<32;i++) c += (x>>i)&1; return c; }

constexpr SignTab make_signs(){
  SignTab t{};
  for(int a=0;a<32;a++) for(int b=0;b<32;b++){
    int swaps=0; int aa=a>>1;
    while(aa){ swaps += popcnt32c(aa & b); aa >>= 1; }
    float s = (swaps & 1) ? -1.0f : 1.0f;
    if ((a & b) & 16) s = -s;   // e5 (bit 4) squares to -1
    t.v[a][b] = s;
  }
  return t;
}
constexpr SignTab GPS = make_signs();

// ---------------- weight repack: wpk[j'][i][o] = w[o][i][SV[j']] -------------
__global__ __launch_bounds__(256) void repack_w(const float* __restrict__ w,
                                                float* __restrict__ wpk){
  int idx = blockIdx.x*256 + threadIdx.x;      // 6*128*128 = 98304 exactly
  int o  = idx & 127;
  int i  = (idx >> 7) & 127;
  int jp = idx >> 14;
  const int SV[6] = {0,1,2,4,8,16};
  wpk[idx] = w[(o*128 + i)*32 + SV[jp]];
}

// ---------------- geometric linear + normalize -------------------------------
// xin: (BS, 128, 32); wpk: (6,128,128); out head-split (b,h,s,d,32) or flat (bs,o,32)
__global__ __launch_bounds__(256) void geo_linear(const float* __restrict__ xin,
                                                  const float* __restrict__ wpk,
                                                  float* __restrict__ out,
                                                  int head_split){
  __shared__ float xs[2*128*32];
  int t = threadIdx.x;
  int bs0 = blockIdx.x * 2;

  const float4* xg = (const float4*)(xin + (size_t)bs0*128*32);
  float4* xl = (float4*)xs;
  #pragma unroll
  for (int r=0;r<8;r++) xl[t + r*256] = xg[t + r*256];
  __syncthreads();

  int bsl = t >> 7;
  int o   = t & 127;
  int bs  = bs0 + bsl;

  float acc[32];
  #pragma unroll
  for(int c=0;c<32;c++) acc[c]=0.0f;

  const float* xrow = xs + bsl*128*32;
  const int SVA[6] = {0,1,2,4,8,16};

  for (int i=0;i<128;i++){
    float xv[32];
    const float4* xr4 = (const float4*)(xrow + i*32);
    #pragma unroll
    for(int l4=0;l4<8;l4++){
      float4 v = xr4[l4];
      xv[4*l4+0]=v.x; xv[4*l4+1]=v.y; xv[4*l4+2]=v.z; xv[4*l4+3]=v.w;
    }
    float wv[6];
    #pragma unroll
    for(int jp=0;jp<6;jp++) wv[jp] = wpk[(jp*128 + i)*128 + o];

    #pragma unroll
    for(int jp=0;jp<6;jp++){
      int j = SVA[jp];
      #pragma unroll
      for(int k=0;k<32;k++){
        // out[k] += w[j] * sign(j, j^k) * x[j^k]
        acc[k] = fmaf(GPS.v[j][j^k] * wv[jp], xv[j^k], acc[k]);
      }
    }
  }

  float ssum = 1e-8f;
  #pragma unroll
  for(int c=0;c<32;c++) ssum = fmaf(acc[c], acc[c], ssum);
  float inv = 1.0f / sqrtf(ssum);

  size_t obase;
  if (head_split){
    int b = bs / SS, s = bs - b*SS;
    int h = o >> 4, d = o & 15;
    obase = ((size_t)(b*NH + h)*SS + s)*512 + d*32;
  } else {
    obase = ((size_t)bs*128 + o)*32;
  }
  float4* og = (float4*)(out + obase);
  #pragma unroll
  for(int l4=0;l4<8;l4++){
    float4 v;
    v.x = acc[4*l4+0]*inv; v.y = acc[4*l4+1]*inv;
    v.z = acc[4*l4+2]*inv; v.w = acc[4*l4+3]*inv;
    og[l4] = v;
  }
}

// ---------------- attention scores -------------------------------------------
// q,k: (BH, S, HDIM, 32).  sc: (BH, S, S).
// raw[k] = sum_d sum_{i,j} sign(i,j) q[d,i] k[d,j]  (k = i^j), then
// score = (raw_hat[0] + lambda*||bivec(raw_hat)||)/4
__global__ __launch_bounds__(256) void scores_k(const float* __restrict__ q,
                                                const float* __restrict__ kk,
                                                float* __restrict__ sc,
                                                const float* __restrict__ lam){
  __shared__ float qs[16][16][36];   // [d][sl][lane(pad)]
  __shared__ float ks[16][16][36];
  int xt = blockIdx.x, st = blockIdx.y, bh = blockIdx.z;
  int t = threadIdx.x;

  const float4* qg = (const float4*)(q + ((size_t)bh*SS + st*16)*512);
  const float4* kg = (const float4*)(kk + ((size_t)bh*SS + xt*16)*512);
  #pragma unroll
  for(int r=0;r<8;r++){
    int f = t + r*256;
    int sl = f >> 7, d = (f>>3)&15, l4 = f&7;
    float4 v = qg[f];
    *(float4*)&qs[d][sl][l4*4] = v;
    float4 u = kg[f];
    *(float4*)&ks[d][sl][l4*4] = u;
  }
  __syncthreads();

  int sl = t >> 4, xl = t & 15;
  float acc[32];
  #pragma unroll
  for(int c=0;c<32;c++) acc[c]=0.0f;

  for(int d=0; d<16; d++){
    float qv[32], kv[32];
    #pragma unroll
    for(int l4=0;l4<8;l4++){
      float4 v = *(const float4*)&qs[d][sl][l4*4];
      qv[4*l4+0]=v.x; qv[4*l4+1]=v.y; qv[4*l4+2]=v.z; qv[4*l4+3]=v.w;
      float4 u = *(const float4*)&ks[d][xl][l4*4];
      kv[4*l4+0]=u.x; kv[4*l4+1]=u.y; kv[4*l4+2]=u.z; kv[4*l4+3]=u.w;
    }
    #pragma unroll
    for(int i=0;i<32;i++){
      #pragma unroll
      for(int j=0;j<32;j++){
        acc[i^j] = fmaf(GPS.v[i][j] * qv[i], kv[j], acc[i^j]);
      }
    }
  }

  float ssum = 1e-8f;
  #pragma unroll
  for(int c=0;c<32;c++) ssum = fmaf(acc[c], acc[c], ssum);
  float inv = 1.0f / sqrtf(ssum);
  float scal = acc[0] * inv;

  const int BIV[10] = {3,5,6,9,10,12,17,18,20,24};
  float bb = 1e-8f;
  #pragma unroll
  for(int c=0;c<10;c++){ float v = acc[BIV[c]]*inv; bb = fmaf(v,v,bb); }

  float score = (scal + lam[0]*sqrtf(bb)) * 0.25f;
  sc[((size_t)bh*SS + st*16 + sl)*SS + xt*16 + xl] = score;
}

// ---------------- softmax over rows of 384 -----------------------------------
__global__ __launch_bounds__(64) void softmax_k(float* __restrict__ sc){
  size_t row = blockIdx.x;
  float* p = sc + row*SS;
  int t = threadIdx.x;
  float v[6];
  float mx = -1e30f;
  #pragma unroll
  for(int r=0;r<6;r++){ v[r] = p[t + r*64]; mx = fmaxf(mx, v[r]); }
  #pragma unroll
  for(int off=32; off; off>>=1) mx = fmaxf(mx, __shfl_xor(mx, off));
  float sum = 0.0f;
  #pragma unroll
  for(int r=0;r<6;r++){ v[r] = __expf(v[r]-mx); sum += v[r]; }
  #pragma unroll
  for(int off=32; off; off>>=1) sum += __shfl_xor(sum, off);
  float inv = 1.0f/sum;
  #pragma unroll
  for(int r=0;r<6;r++) p[t + r*64] = v[r]*inv;
}

// ---------------- P @ V + head merge -----------------------------------------
// pr: (BH,S,S) probs; v: (BH,S,512); om: (BS,128,32) merged
__global__ __launch_bounds__(256) void pv_k(const float* __restrict__ pr,
                                            const float* __restrict__ v,
                                            float* __restrict__ om){
  __shared__ float ps[16][64];
  int st = blockIdx.x;   // 24
  int bh = blockIdx.y;   // 16
  int t = threadIdx.x;

  float acc[32];         // [sl][2]
  #pragma unroll
  for(int z=0;z<32;z++) acc[z]=0.0f;

  const float* vbase = v + (size_t)bh*SS*512;
  for(int xc=0; xc<SS; xc+=64){
    __syncthreads();
    #pragma unroll
    for(int r=0;r<4;r++){
      int f = t + r*256;
      int sl = f >> 6, xx = f & 63;
      ps[sl][xx] = pr[((size_t)bh*SS + st*16 + sl)*SS + xc + xx];
    }
    __syncthreads();
    for(int xx=0; xx<64; xx+=2){
      float2 vv0 = *(const float2*)(vbase + (size_t)(xc+xx  )*512 + t*2);
      float2 vv1 = *(const float2*)(vbase + (size_t)(xc+xx+1)*512 + t*2);
      #pragma unroll
      for(int sl=0;sl<16;sl++){
        float2 pp = *(const float2*)&ps[sl][xx];
        acc[sl*2+0] = fmaf(pp.x, vv0.x, acc[sl*2+0]);
        acc[sl*2+1] = fmaf(pp.x, vv0.y, acc[sl*2+1]);
        acc[sl*2+0] = fmaf(pp.y, vv1.x, acc[sl*2+0]);
        acc[sl*2+1] = fmaf(pp.y, vv1.y, acc[sl*2+1]);
      }
    }
  }

  int b = bh >> 3, h = bh & 7;
  int c0 = t*2; int d = c0 >> 5; int l = c0 & 31;
  #pragma unroll
  for(int sl=0; sl<16; sl++){
    int s = st*16 + sl;
    float2 w2; w2.x = acc[sl*2]; w2.y = acc[sl*2+1];
    *(float2*)(om + ((size_t)(b*SS + s)*128 + h*16 + d)*32 + l) = w2;
  }
}

// ---------------- launch ------------------------------------------------------
extern "C" void kernel_launch(void* const* d_in, const int* in_sizes, int n_in,
                              void* d_out, int out_size, void* d_ws, size_t ws_size,
                              hipStream_t stream) {
  const float* x   = (const float*)d_in[0];
  const float* wq  = (const float*)d_in[1];
  const float* wk  = (const float*)d_in[2];
  const float* wv  = (const float*)d_in[3];
  const float* wo  = (const float*)d_in[4];
  const float* lam = (const float*)d_in[5];
  float* out = (float*)d_out;

  float* ws = (float*)d_ws;
  size_t off = 0;
  float* wpkq = ws + off; off += 6*128*128;
  float* wpkk = ws + off; off += 6*128*128;
  float* wpkv = ws + off; off += 6*128*128;
  float* wpko = ws + off; off += 6*128*128;
  float* qb = ws + off; off += (size_t)NBH*SS*512;
  float* kb = ws + off; off += (size_t)NBH*SS*512;
  float* vb = ws + off; off += (size_t)NBH*SS*512;
  float* sc = ws + off; off += (size_t)NBH*SS*SS;
  float* om = ws + off; off += (size_t)BS*128*32;

  repack_w<<<384,256,0,stream>>>(wq, wpkq);
  repack_w<<<384,256,0,stream>>>(wk, wpkk);
  repack_w<<<384,256,0,stream>>>(wv, wpkv);
  repack_w<<<384,256,0,stream>>>(wo, wpko);

  geo_linear<<<384,256,0,stream>>>(x, wpkq, qb, 1);
  geo_linear<<<384,256,0,stream>>>(x, wpkk, kb, 1);
  geo_linear<<<384,256,0,stream>>>(x, wpkv, vb, 1);

  scores_k<<<dim3(24,24,16),256,0,stream>>>(qb, kb, sc, lam);
  softmax_k<<<NBH*SS,64,0,stream>>>(sc);
  pv_k<<<dim3(24,16),256,0,stream>>>(sc, vb, om);

  geo_linear<<<384,256,0,stream>>>(om, wpko, out, 0);
}

// Round 2
// 587.225 us; speedup vs baseline: 2.1130x; 2.1130x over previous
//
#include <hip/hip_runtime.h>
#include <math.h>

// Problem constants
#define BB    2
#define SS    384
#define DD    128
#define NH    8
#define HDIM  16
#define NBH   16      // B*H
#define BS    768     // B*S

typedef unsigned int   u32;
typedef unsigned short u16;
typedef __attribute__((ext_vector_type(8))) short short8;
typedef __attribute__((ext_vector_type(4))) float f32x4;

// ---------------- compile-time Cl(4,1) geometric-product sign table ----------
struct SignTab { float v[32][32]; };

constexpr int popcnt32c(int x){ int c=0; for(int i=0;i<32;i++) c += (x>>i)&1; return c; }

constexpr int signgp_int(int a, int b){
  int swaps=0; int aa=a>>1;
  while(aa){ swaps += popcnt32c(aa & b); aa >>= 1; }
  int s = (swaps & 1) ? -1 : 1;
  if ((a & b) & 16) s = -s;   // e5 (bit 4) squares to -1
  return s;
}

constexpr SignTab make_signs(){
  SignTab t{};
  for(int a=0;a<32;a++) for(int b=0;b<32;b++)
    t.v[a][b] = (float)signgp_int(a,b);
  return t;
}
constexpr SignTab GPS = make_signs();

// Sign-bit XOR masks for the B fragment of blade c=(w<<3)|u.
// Element at lane-quad q, position j (k = q*8+j) multiplies K[i^c] by
// sign(i, i^c) with i = q*8+j. Packed: j=2r -> bit15 of word r, j=2r+1 -> bit31.
struct MaskTab { u32 v[4][8][4][4]; };
constexpr MaskTab mkmask(){
  MaskTab t{};
  for(int w=0;w<4;w++) for(int u=0;u<8;u++) for(int q=0;q<4;q++) for(int r=0;r<4;r++){
    u32 m = 0;
    for(int h=0;h<2;h++){
      int j = 2*r + h;
      int i = (q<<3) | j;
      int c = (w<<3) | u;
      if (signgp_int(i, i^c) < 0) m |= (h ? 0x80000000u : 0x8000u);
    }
    t.v[w][u][q][r] = m;
  }
  return t;
}
constexpr MaskTab MT = mkmask();

__device__ __forceinline__ u16 f2bf(float f){   // round-to-nearest-even
  u32 x = __float_as_uint(f);
  return (u16)((x + 0x7FFFu + ((x>>16)&1u)) >> 16);
}

// ---------------- weight repack: wpk[j'][i][o] = w[o][i][SV[j']] -------------
__global__ __launch_bounds__(256) void repack_w(const float* __restrict__ w,
                                                float* __restrict__ wpk){
  int idx = blockIdx.x*256 + threadIdx.x;      // 6*128*128 = 98304 exactly
  int o  = idx & 127;
  int i  = (idx >> 7) & 127;
  int jp = idx >> 14;
  const int SV[6] = {0,1,2,4,8,16};
  wpk[idx] = w[(o*128 + i)*32 + SV[jp]];
}

// ---------------- geometric linear + normalize -------------------------------
// xin: (BS, 128, 32); wpk: (6,128,128)
// mode 0: out fp32 flat (bs,o,32); mode 1: out fp32 head-split (b,h,s,d,32);
// mode 2: out bf16 head-split.
__global__ __launch_bounds__(256) void geo_linear(const float* __restrict__ xin,
                                                  const float* __restrict__ wpk,
                                                  void* __restrict__ outp,
                                                  int mode){
  __shared__ float xs[2*128*32];
  int t = threadIdx.x;
  int bs0 = blockIdx.x * 2;

  const float4* xg = (const float4*)(xin + (size_t)bs0*128*32);
  float4* xl = (float4*)xs;
  #pragma unroll
  for (int r=0;r<8;r++) xl[t + r*256] = xg[t + r*256];
  __syncthreads();

  int bsl = t >> 7;
  int o   = t & 127;
  int bs  = bs0 + bsl;

  float acc[32];
  #pragma unroll
  for(int c=0;c<32;c++) acc[c]=0.0f;

  const float* xrow = xs + bsl*128*32;
  const int SVA[6] = {0,1,2,4,8,16};

  for (int i=0;i<128;i++){
    float xv[32];
    const float4* xr4 = (const float4*)(xrow + i*32);
    #pragma unroll
    for(int l4=0;l4<8;l4++){
      float4 v = xr4[l4];
      xv[4*l4+0]=v.x; xv[4*l4+1]=v.y; xv[4*l4+2]=v.z; xv[4*l4+3]=v.w;
    }
    float wv[6];
    #pragma unroll
    for(int jp=0;jp<6;jp++) wv[jp] = wpk[(jp*128 + i)*128 + o];

    #pragma unroll
    for(int jp=0;jp<6;jp++){
      int j = SVA[jp];
      #pragma unroll
      for(int k=0;k<32;k++){
        acc[k] = fmaf(GPS.v[j][j^k] * wv[jp], xv[j^k], acc[k]);
      }
    }
  }

  float ssum = 1e-8f;
  #pragma unroll
  for(int c=0;c<32;c++) ssum = fmaf(acc[c], acc[c], ssum);
  float inv = 1.0f / sqrtf(ssum);

  size_t obase;
  if (mode != 0){
    int b = bs / SS, s = bs - b*SS;
    int h = o >> 4, d = o & 15;
    obase = ((size_t)(b*NH + h)*SS + s)*512 + d*32;
  } else {
    obase = ((size_t)bs*128 + o)*32;
  }

  if (mode == 2){
    u16 us[32];
    #pragma unroll
    for(int c=0;c<32;c++) us[c] = f2bf(acc[c]*inv);
    uint4* og = (uint4*)((u16*)outp + obase);
    #pragma unroll
    for(int l=0;l<4;l++){
      uint4 v;
      v.x = (u32)us[8*l+0] | ((u32)us[8*l+1]<<16);
      v.y = (u32)us[8*l+2] | ((u32)us[8*l+3]<<16);
      v.z = (u32)us[8*l+4] | ((u32)us[8*l+5]<<16);
      v.w = (u32)us[8*l+6] | ((u32)us[8*l+7]<<16);
      og[l] = v;
    }
  } else {
    float4* og = (float4*)((float*)outp + obase);
    #pragma unroll
    for(int l4=0;l4<8;l4++){
      float4 v;
      v.x = acc[4*l4+0]*inv; v.y = acc[4*l4+1]*inv;
      v.z = acc[4*l4+2]*inv; v.w = acc[4*l4+3]*inv;
      og[l4] = v;
    }
  }
}

// ---------------- MFMA attention scores --------------------------------------
// qh,kh: bf16 (BH, S, 16, 32) [inner 512 = d*32+i]. sc: (BH,S,S) fp32.
// Per WG: 16 s x 16 x tile; wave w computes blades c = w*8+u, u=0..7.
// raw_c = Q(16x512) . K'_c(512x16), K'_c[n][k=(d,i)] = sign(i,i^c) K[n][d][i^c].
#define LPAD 528   // LDS row stride in ushorts (16B-aligned, de-conflicted)
__global__ __launch_bounds__(256) void scores_mfma(const u16* __restrict__ qh,
                                                   const u16* __restrict__ kh,
                                                   float* __restrict__ sc,
                                                   const float* __restrict__ lam){
  __shared__ __align__(16) u16 smem[2*16*LPAD];
  u16* qs = smem;
  u16* ks = smem + 16*LPAD;
  int t = threadIdx.x;
  int xt = blockIdx.x, st = blockIdx.y, bh = blockIdx.z;

  const uint4* qg = (const uint4*)(qh + ((size_t)bh*SS + st*16)*512);
  const uint4* kg = (const uint4*)(kh + ((size_t)bh*SS + xt*16)*512);
  #pragma unroll
  for(int r=0;r<4;r++){
    int f = t + r*256;            // 1024 uint4 = 16 rows x 64
    int row = f >> 6;
    int col = (f & 63) * 8;
    *(uint4*)(qs + row*LPAD + col) = qg[f];
    *(uint4*)(ks + row*LPAD + col) = kg[f];
  }
  __syncthreads();

  int w    = t >> 6;
  int lane = t & 63;
  int q    = lane >> 4;
  int mn   = lane & 15;

  u32 FM[8][4];
  #pragma unroll
  for(int u=0;u<8;u++)
    #pragma unroll
    for(int r=0;r<4;r++) FM[u][r] = MT.v[w][u][q][r];

  f32x4 acc[8];
  #pragma unroll
  for(int u=0;u<8;u++) acc[u] = (f32x4){0.f,0.f,0.f,0.f};

  const u16* qrow = qs + mn*LPAD + q*8;
  const u16* krow = ks + mn*LPAD + ((q^w)<<3);

  for(int kt=0; kt<16; kt++){
    short8 a   = *(const short8*)(qrow + kt*32);
    uint4 khd  = *(const uint4*)(krow + kt*32);
    u32 kk[4] = {khd.x, khd.y, khd.z, khd.w};
    #pragma unroll
    for(int u=0;u<8;u++){
      union { u32 w32[4]; short8 s; } bf;
      #pragma unroll
      for(int r=0;r<4;r++){
        u32 v = kk[r ^ (u>>1)];
        if (u & 1) v = (v>>16)|(v<<16);   // odd u: swap halfwords
        bf.w32[r] = v ^ FM[u][r];
      }
      acc[u] = __builtin_amdgcn_mfma_f32_16x16x32_bf16(a, bf.s, acc[u], 0, 0, 0);
    }
  }
  __syncthreads();

  // ---- reduce 32 blades -> score, overlaying the staging LDS ----
  float* pss = (float*)smem;          // [4][16][17]
  float* pbb = pss + 4*16*17;         // [4][16][17]
  float* ps0 = pbb + 4*16*17;         // [16][17]

  float ssp[4] = {0,0,0,0}, bbp[4] = {0,0,0,0};
  #pragma unroll
  for(int u=0;u<8;u++){
    int c = w*8 + u;
    bool isb = (c==3)||(c==5)||(c==6)||(c==9)||(c==10)||(c==12)||
               (c==17)||(c==18)||(c==20)||(c==24);
    #pragma unroll
    for(int r=0;r<4;r++){
      float v = acc[u][r];
      ssp[r] = fmaf(v, v, ssp[r]);
      if (isb) bbp[r] = fmaf(v, v, bbp[r]);
    }
  }
  #pragma unroll
  for(int r=0;r<4;r++){
    int s = q*4 + r;                  // C-layout: row = quad*4 + reg
    pss[(w*16 + s)*17 + mn] = ssp[r];
    pbb[(w*16 + s)*17 + mn] = bbp[r];
    if (w == 0) ps0[s*17 + mn] = acc[0][r];
  }
  __syncthreads();

  int s = t >> 4, x = t & 15;
  float ss = 1e-8f, bb = 0.f;
  #pragma unroll
  for(int ww=0; ww<4; ww++){
    ss += pss[(ww*16+s)*17+x];
    bb += pbb[(ww*16+s)*17+x];
  }
  float inv = 1.0f / sqrtf(ss);
  float s0  = ps0[s*17+x];
  float score = (s0*inv + lam[0]*sqrtf(bb*inv*inv + 1e-8f)) * 0.25f;
  sc[((size_t)bh*SS + st*16 + s)*SS + xt*16 + x] = score;
}

// ---------------- softmax over rows of 384 -----------------------------------
__global__ __launch_bounds__(64) void softmax_k(float* __restrict__ sc){
  size_t row = blockIdx.x;
  float* p = sc + row*SS;
  int t = threadIdx.x;
  float v[6];
  float mx = -1e30f;
  #pragma unroll
  for(int r=0;r<6;r++){ v[r] = p[t + r*64]; mx = fmaxf(mx, v[r]); }
  #pragma unroll
  for(int off=32; off; off>>=1) mx = fmaxf(mx, __shfl_xor(mx, off));
  float sum = 0.0f;
  #pragma unroll
  for(int r=0;r<6;r++){ v[r] = __expf(v[r]-mx); sum += v[r]; }
  #pragma unroll
  for(int off=32; off; off>>=1) sum += __shfl_xor(sum, off);
  float inv = 1.0f/sum;
  #pragma unroll
  for(int r=0;r<6;r++) p[t + r*64] = v[r]*inv;
}

// ---------------- P @ V + head merge -----------------------------------------
__global__ __launch_bounds__(256) void pv_k(const float* __restrict__ pr,
                                            const float* __restrict__ v,
                                            float* __restrict__ om){
  __shared__ float ps[16][64];
  int st = blockIdx.x;
  int bh = blockIdx.y;
  int t = threadIdx.x;

  float acc[32];
  #pragma unroll
  for(int z=0;z<32;z++) acc[z]=0.0f;

  const float* vbase = v + (size_t)bh*SS*512;
  for(int xc=0; xc<SS; xc+=64){
    __syncthreads();
    #pragma unroll
    for(int r=0;r<4;r++){
      int f = t + r*256;
      int sl = f >> 6, xx = f & 63;
      ps[sl][xx] = pr[((size_t)bh*SS + st*16 + sl)*SS + xc + xx];
    }
    __syncthreads();
    for(int xx=0; xx<64; xx+=2){
      float2 vv0 = *(const float2*)(vbase + (size_t)(xc+xx  )*512 + t*2);
      float2 vv1 = *(const float2*)(vbase + (size_t)(xc+xx+1)*512 + t*2);
      #pragma unroll
      for(int sl=0;sl<16;sl++){
        float2 pp = *(const float2*)&ps[sl][xx];
        acc[sl*2+0] = fmaf(pp.x, vv0.x, acc[sl*2+0]);
        acc[sl*2+1] = fmaf(pp.x, vv0.y, acc[sl*2+1]);
        acc[sl*2+0] = fmaf(pp.y, vv1.x, acc[sl*2+0]);
        acc[sl*2+1] = fmaf(pp.y, vv1.y, acc[sl*2+1]);
      }
    }
  }

  int b = bh >> 3, h = bh & 7;
  int c0 = t*2; int d = c0 >> 5; int l = c0 & 31;
  #pragma unroll
  for(int sl=0; sl<16; sl++){
    int s = st*16 + sl;
    float2 w2; w2.x = acc[sl*2]; w2.y = acc[sl*2+1];
    *(float2*)(om + ((size_t)(b*SS + s)*128 + h*16 + d)*32 + l) = w2;
  }
}

// ---------------- launch ------------------------------------------------------
extern "C" void kernel_launch(void* const* d_in, const int* in_sizes, int n_in,
                              void* d_out, int out_size, void* d_ws, size_t ws_size,
                              hipStream_t stream) {
  const float* x   = (const float*)d_in[0];
  const float* wq  = (const float*)d_in[1];
  const float* wk  = (const float*)d_in[2];
  const float* wv  = (const float*)d_in[3];
  const float* wo  = (const float*)d_in[4];
  const float* lam = (const float*)d_in[5];
  float* out = (float*)d_out;

  char* ws = (char*)d_ws;
  size_t off = 0;
  float* wpkq = (float*)(ws + off); off += 6*128*128*4;
  float* wpkk = (float*)(ws + off); off += 6*128*128*4;
  float* wpkv = (float*)(ws + off); off += 6*128*128*4;
  float* wpko = (float*)(ws + off); off += 6*128*128*4;
  u16*   qhb  = (u16*)  (ws + off); off += (size_t)NBH*SS*512*2;
  u16*   khb  = (u16*)  (ws + off); off += (size_t)NBH*SS*512*2;
  float* vb   = (float*)(ws + off); off += (size_t)NBH*SS*512*4;
  float* sc   = (float*)(ws + off); off += (size_t)NBH*SS*SS*4;
  float* om   = (float*)(ws + off); off += (size_t)BS*128*32*4;

  repack_w<<<384,256,0,stream>>>(wq, wpkq);
  repack_w<<<384,256,0,stream>>>(wk, wpkk);
  repack_w<<<384,256,0,stream>>>(wv, wpkv);
  repack_w<<<384,256,0,stream>>>(wo, wpko);

  geo_linear<<<384,256,0,stream>>>(x, wpkq, qhb, 2);   // bf16 head-split
  geo_linear<<<384,256,0,stream>>>(x, wpkk, khb, 2);   // bf16 head-split
  geo_linear<<<384,256,0,stream>>>(x, wpkv, vb, 1);    // fp32 head-split

  scores_mfma<<<dim3(24,24,16),256,0,stream>>>(qhb, khb, sc, lam);
  softmax_k<<<NBH*SS,64,0,stream>>>(sc);
  pv_k<<<dim3(24,16),256,0,stream>>>(sc, vb, om);

  geo_linear<<<384,256,0,stream>>>(om, wpko, out, 0);
}

// Round 3
// 338.701 us; speedup vs baseline: 3.6634x; 1.7338x over previous
//
#include <hip/hip_runtime.h>
#include <math.h>

// Problem constants
#define BB    2
#define SS    384
#define DD    128
#define NH    8
#define HDIM  16
#define NBH   16      // B*H
#define BS    768     // B*S

typedef unsigned int   u32;
typedef unsigned short u16;
typedef __attribute__((ext_vector_type(8))) short short8;
typedef __attribute__((ext_vector_type(4))) float f32x4;

// ---------------- compile-time Cl(4,1) geometric-product sign table ----------
struct SignTab { float v[32][32]; };
constexpr int popcnt32c(int x){ int c=0; for(int i=0;i<32;i++) c += (x>>i)&1; return c; }
constexpr int signgp_int(int a, int b){
  int swaps=0; int aa=a>>1;
  while(aa){ swaps += popcnt32c(aa & b); aa >>= 1; }
  int s = (swaps & 1) ? -1 : 1;
  if ((a & b) & 16) s = -s;   // e5 (bit 4) squares to -1
  return s;
}
constexpr SignTab make_signs(){
  SignTab t{};
  for(int a=0;a<32;a++) for(int b=0;b<32;b++)
    t.v[a][b] = (float)signgp_int(a,b);
  return t;
}
constexpr SignTab GPS = make_signs();

// Sign-bit XOR masks for scores B fragment, blade c=(w<<3)|u (unchanged from R2).
struct MaskTab { u32 v[4][8][4][4]; };
constexpr MaskTab mkmask(){
  MaskTab t{};
  for(int w=0;w<4;w++) for(int u=0;u<8;u++) for(int q=0;q<4;q++) for(int r=0;r<4;r++){
    u32 m = 0;
    for(int h=0;h<2;h++){
      int j = 2*r + h;
      int i = (q<<3) | j;
      int c = (w<<3) | u;
      if (signgp_int(i, i^c) < 0) m |= (h ? 0x80000000u : 0x8000u);
    }
    t.v[w][u][q][r] = m;
  }
  return t;
}
constexpr MaskTab MT = mkmask();

__device__ __forceinline__ u16 f2bf(float f){   // round-to-nearest-even
  u32 x = __float_as_uint(f);
  return (u16)((x + 0x7FFFu + ((x>>16)&1u)) >> 16);
}
__device__ __forceinline__ float bf2f(u16 h){
  return __uint_as_float(((u32)h) << 16);
}

// ---------------- weight repack: wpk2[p][o][jp*128+i] = bf16(w_p[o,i,SV[jp]]) -
__global__ __launch_bounds__(256) void repack_wb(const float* __restrict__ wq,
                                                 const float* __restrict__ wk,
                                                 const float* __restrict__ wv,
                                                 const float* __restrict__ wo,
                                                 u16* __restrict__ wpk2){
  int idx = blockIdx.x*256 + threadIdx.x;      // 0..98303
  int p = blockIdx.y;
  const float* w = (p==0)?wq:(p==1)?wk:(p==2)?wv:wo;
  int o   = idx / 768;
  int rem = idx - o*768;
  int jp  = rem >> 7;
  int i   = rem & 127;
  const int SV[6] = {0,1,2,4,8,16};
  wpk2[p*98304 + idx] = f2bf(w[(o*128 + i)*32 + SV[jp]]);
}

// ---------------- blade gather: xg[k][bs][jp*128+i] = sign*src[bs,i,SV[jp]^k] -
// src: (768,128,32) fp32 (flag=0) or bf16 (flag=1). xg bf16 (32,768,768).
#define XLS 33   // LDS row stride (floats) for de-conflicted strided reads
__global__ __launch_bounds__(256) void gather_k(const void* __restrict__ src,
                                                int src_bf16,
                                                u16* __restrict__ xg){
  __shared__ float xl[2*128*XLS];
  int t = threadIdx.x;
  int bs0 = blockIdx.x*2;
  int bsl = t >> 7, i = t & 127;

  float row[32];
  if (src_bf16){
    const uint4* s4 = (const uint4*)((const u16*)src + (((size_t)(bs0+bsl)*128 + i)*32));
    #pragma unroll
    for(int r=0;r<4;r++){
      uint4 v = s4[r];
      u32 ww[4] = {v.x,v.y,v.z,v.w};
      #pragma unroll
      for(int h=0;h<4;h++){
        row[r*8 + 2*h    ] = __uint_as_float(ww[h] << 16);
        row[r*8 + 2*h + 1] = __uint_as_float(ww[h] & 0xFFFF0000u);
      }
    }
  } else {
    const float4* s4 = (const float4*)((const float*)src + (((size_t)(bs0+bsl)*128 + i)*32));
    #pragma unroll
    for(int r=0;r<8;r++){
      float4 v = s4[r];
      row[r*4+0]=v.x; row[r*4+1]=v.y; row[r*4+2]=v.z; row[r*4+3]=v.w;
    }
  }
  float* xrow = xl + bsl*128*XLS + i*XLS;
  #pragma unroll
  for(int l=0;l<32;l++) xrow[l] = row[l];
  __syncthreads();

  const int SV[6] = {0,1,2,4,8,16};
  u32* xg32 = (u32*)xg;
  #pragma unroll 4
  for(int r=0;r<96;r++){
    int wr = t + r*256;            // 0..24575
    int k   = wr / 768;
    int rem = wr - k*768;
    int bl  = rem / 384;
    int r2  = rem - bl*384;
    int jp  = r2 >> 6;
    int ip  = r2 & 63;
    int i2  = ip*2;
    int b   = SV[jp] ^ k;
    float sg = GPS.v[SV[jp]][b];
    const float* base = xl + bl*128*XLS;
    float f0 = base[ i2   *XLS + b] * sg;
    float f1 = base[(i2+1)*XLS + b] * sg;
    u32 pk = (u32)f2bf(f0) | ((u32)f2bf(f1) << 16);
    xg32[((size_t)k*768 + bs0 + bl)*384 + jp*64 + ip] = pk;
  }
}

// ---------------- projection GEMM --------------------------------------------
// Per block (Mt, k, p): C(128 bs x 128 o) = xg[k](768x768) . wpk_p(o x 768)^T
// over K=768. Output tmp[p][k][bs][o] bf16.
#define LSTR 40   // LDS tile row stride in u16 (16B aligned, conflict-friendly)
__global__ __launch_bounds__(256) void gemm_proj(const u16* __restrict__ xg,
                                                 const u16* __restrict__ wpkA,
                                                 u16* __restrict__ tmpA){
  __shared__ __align__(16) u16 As[128*LSTR];
  __shared__ __align__(16) u16 Bs[128*LSTR];
  int t = threadIdx.x;
  int Mt = blockIdx.x, k = blockIdx.y, p = blockIdx.z;
  const u16* wpk = wpkA + (size_t)p*98304;
  u16* tmp = tmpA + (size_t)p*32*768*128;

  int w = t >> 6, lane = t & 63;
  int q = lane >> 4, n16 = lane & 15;
  int wm = w >> 1, wn = w & 1;

  f32x4 acc[4][4];
  #pragma unroll
  for(int a=0;a<4;a++)
    #pragma unroll
    for(int b=0;b<4;b++) acc[a][b] = (f32x4){0.f,0.f,0.f,0.f};

  // staging indices: f in {t, t+256}; row=f>>2, c4=f&3
  int r0 = t>>2, c0 = (t&3)*8;
  int r1 = (t+256)>>2, c1 = ((t+256)&3)*8;
  const u16* Aab = xg + ((size_t)k*768 + Mt*128)*768;

  uint4 pa0, pa1, pb0, pb1;
  {
    pa0 = *(const uint4*)(Aab + (size_t)r0*768 + c0);
    pa1 = *(const uint4*)(Aab + (size_t)r1*768 + c1);
    pb0 = *(const uint4*)(wpk + (size_t)r0*768 + c0);
    pb1 = *(const uint4*)(wpk + (size_t)r1*768 + c1);
  }

  for(int kt=0; kt<24; kt++){
    __syncthreads();
    *(uint4*)(As + r0*LSTR + c0) = pa0;
    *(uint4*)(As + r1*LSTR + c1) = pa1;
    *(uint4*)(Bs + r0*LSTR + c0) = pb0;
    *(uint4*)(Bs + r1*LSTR + c1) = pb1;
    __syncthreads();
    if (kt < 23){
      int kn = (kt+1)*32;
      pa0 = *(const uint4*)(Aab + (size_t)r0*768 + kn + c0);
      pa1 = *(const uint4*)(Aab + (size_t)r1*768 + kn + c1);
      pb0 = *(const uint4*)(wpk + (size_t)r0*768 + kn + c0);
      pb1 = *(const uint4*)(wpk + (size_t)r1*768 + kn + c1);
    }
    short8 a[4], b[4];
    #pragma unroll
    for(int mi=0;mi<4;mi++)
      a[mi] = *(const short8*)(As + (wm*64 + mi*16 + n16)*LSTR + q*8);
    #pragma unroll
    for(int ni=0;ni<4;ni++)
      b[ni] = *(const short8*)(Bs + (wn*64 + ni*16 + n16)*LSTR + q*8);
    #pragma unroll
    for(int mi=0;mi<4;mi++)
      #pragma unroll
      for(int ni=0;ni<4;ni++)
        acc[mi][ni] = __builtin_amdgcn_mfma_f32_16x16x32_bf16(a[mi], b[ni], acc[mi][ni], 0,0,0);
  }

  #pragma unroll
  for(int mi=0;mi<4;mi++){
    #pragma unroll
    for(int r=0;r<4;r++){
      int m = Mt*128 + wm*64 + mi*16 + q*4 + r;
      #pragma unroll
      for(int ni=0;ni<4;ni++){
        int n = wn*64 + ni*16 + n16;
        tmp[((size_t)k*768 + m)*128 + n] = f2bf(acc[mi][ni][r]);
      }
    }
  }
}

// ---------------- normalize + layout -----------------------------------------
// tmp: bf16 (32,768,128) for one projection. mode 1: bf16 head-split
// (b,h,s,d,32); mode 0: fp32 flat (bs,o,32).
__global__ __launch_bounds__(256) void norm_split(const u16* __restrict__ tmp,
                                                  void* __restrict__ dst,
                                                  int mode){
  int t = threadIdx.x;
  int bsl = t >> 7, o = t & 127;
  int bs = blockIdx.x*2 + bsl;

  float a[32];
  float ssum = 1e-8f;
  #pragma unroll
  for(int k=0;k<32;k++){
    a[k] = bf2f(tmp[((size_t)k*768 + bs)*128 + o]);
    ssum = fmaf(a[k], a[k], ssum);
  }
  float inv = 1.0f / sqrtf(ssum);

  if (mode == 1){
    int b = bs / SS, s = bs - b*SS;
    int h = o >> 4, d = o & 15;
    u16* og = (u16*)dst + (((size_t)(b*NH + h)*SS + s)*512 + d*32);
    uint4* og4 = (uint4*)og;
    #pragma unroll
    for(int l=0;l<4;l++){
      uint4 v;
      v.x = (u32)f2bf(a[8*l+0]*inv) | ((u32)f2bf(a[8*l+1]*inv)<<16);
      v.y = (u32)f2bf(a[8*l+2]*inv) | ((u32)f2bf(a[8*l+3]*inv)<<16);
      v.z = (u32)f2bf(a[8*l+4]*inv) | ((u32)f2bf(a[8*l+5]*inv)<<16);
      v.w = (u32)f2bf(a[8*l+6]*inv) | ((u32)f2bf(a[8*l+7]*inv)<<16);
      og4[l] = v;
    }
  } else {
    float4* og = (float4*)((float*)dst + ((size_t)bs*128 + o)*32);
    #pragma unroll
    for(int l4=0;l4<8;l4++){
      float4 v;
      v.x = a[4*l4+0]*inv; v.y = a[4*l4+1]*inv;
      v.z = a[4*l4+2]*inv; v.w = a[4*l4+3]*inv;
      og[l4] = v;
    }
  }
}

// ---------------- MFMA attention scores (unchanged from R2) ------------------
#define LPAD 528
__global__ __launch_bounds__(256) void scores_mfma(const u16* __restrict__ qh,
                                                   const u16* __restrict__ kh,
                                                   float* __restrict__ sc,
                                                   const float* __restrict__ lam){
  __shared__ __align__(16) u16 smem[2*16*LPAD];
  u16* qs = smem;
  u16* ks = smem + 16*LPAD;
  int t = threadIdx.x;
  int xt = blockIdx.x, st = blockIdx.y, bh = blockIdx.z;

  const uint4* qg = (const uint4*)(qh + ((size_t)bh*SS + st*16)*512);
  const uint4* kg = (const uint4*)(kh + ((size_t)bh*SS + xt*16)*512);
  #pragma unroll
  for(int r=0;r<4;r++){
    int f = t + r*256;
    int row = f >> 6;
    int col = (f & 63) * 8;
    *(uint4*)(qs + row*LPAD + col) = qg[f];
    *(uint4*)(ks + row*LPAD + col) = kg[f];
  }
  __syncthreads();

  int w    = t >> 6;
  int lane = t & 63;
  int q    = lane >> 4;
  int mn   = lane & 15;

  u32 FM[8][4];
  #pragma unroll
  for(int u=0;u<8;u++)
    #pragma unroll
    for(int r=0;r<4;r++) FM[u][r] = MT.v[w][u][q][r];

  f32x4 acc[8];
  #pragma unroll
  for(int u=0;u<8;u++) acc[u] = (f32x4){0.f,0.f,0.f,0.f};

  const u16* qrow = qs + mn*LPAD + q*8;
  const u16* krow = ks + mn*LPAD + ((q^w)<<3);

  for(int kt=0; kt<16; kt++){
    short8 a   = *(const short8*)(qrow + kt*32);
    uint4 khd  = *(const uint4*)(krow + kt*32);
    u32 kk[4] = {khd.x, khd.y, khd.z, khd.w};
    #pragma unroll
    for(int u=0;u<8;u++){
      union { u32 w32[4]; short8 s; } bf;
      #pragma unroll
      for(int r=0;r<4;r++){
        u32 v = kk[r ^ (u>>1)];
        if (u & 1) v = (v>>16)|(v<<16);
        bf.w32[r] = v ^ FM[u][r];
      }
      acc[u] = __builtin_amdgcn_mfma_f32_16x16x32_bf16(a, bf.s, acc[u], 0, 0, 0);
    }
  }
  __syncthreads();

  float* pss = (float*)smem;          // [4][16][17]
  float* pbb = pss + 4*16*17;
  float* ps0 = pbb + 4*16*17;

  float ssp[4] = {0,0,0,0}, bbp[4] = {0,0,0,0};
  #pragma unroll
  for(int u=0;u<8;u++){
    int c = w*8 + u;
    bool isb = (c==3)||(c==5)||(c==6)||(c==9)||(c==10)||(c==12)||
               (c==17)||(c==18)||(c==20)||(c==24);
    #pragma unroll
    for(int r=0;r<4;r++){
      float v = acc[u][r];
      ssp[r] = fmaf(v, v, ssp[r]);
      if (isb) bbp[r] = fmaf(v, v, bbp[r]);
    }
  }
  #pragma unroll
  for(int r=0;r<4;r++){
    int s = q*4 + r;
    pss[(w*16 + s)*17 + mn] = ssp[r];
    pbb[(w*16 + s)*17 + mn] = bbp[r];
    if (w == 0) ps0[s*17 + mn] = acc[0][r];
  }
  __syncthreads();

  int s = t >> 4, x = t & 15;
  float ss = 1e-8f, bb = 0.f;
  #pragma unroll
  for(int ww=0; ww<4; ww++){
    ss += pss[(ww*16+s)*17+x];
    bb += pbb[(ww*16+s)*17+x];
  }
  float inv = 1.0f / sqrtf(ss);
  float s0  = ps0[s*17+x];
  float score = (s0*inv + lam[0]*sqrtf(bb*inv*inv + 1e-8f)) * 0.25f;
  sc[((size_t)bh*SS + st*16 + s)*SS + xt*16 + x] = score;
}

// ---------------- softmax over rows of 384 -----------------------------------
__global__ __launch_bounds__(64) void softmax_k(float* __restrict__ sc){
  size_t row = blockIdx.x;
  float* p = sc + row*SS;
  int t = threadIdx.x;
  float v[6];
  float mx = -1e30f;
  #pragma unroll
  for(int r=0;r<6;r++){ v[r] = p[t + r*64]; mx = fmaxf(mx, v[r]); }
  #pragma unroll
  for(int off=32; off; off>>=1) mx = fmaxf(mx, __shfl_xor(mx, off));
  float sum = 0.0f;
  #pragma unroll
  for(int r=0;r<6;r++){ v[r] = __expf(v[r]-mx); sum += v[r]; }
  #pragma unroll
  for(int off=32; off; off>>=1) sum += __shfl_xor(sum, off);
  float inv = 1.0f/sum;
  #pragma unroll
  for(int r=0;r<6;r++) p[t + r*64] = v[r]*inv;
}

// ---------------- P @ V + head merge (bf16 V in, bf16 om out) ----------------
__global__ __launch_bounds__(256) void pv_k(const float* __restrict__ pr,
                                            const u16* __restrict__ v,
                                            u16* __restrict__ om){
  __shared__ float ps[16][64];
  int st = blockIdx.x;
  int bh = blockIdx.y;
  int t = threadIdx.x;

  float acc[32];
  #pragma unroll
  for(int z=0;z<32;z++) acc[z]=0.0f;

  const u32* vbase = (const u32*)v + (size_t)bh*SS*256;
  for(int xc=0; xc<SS; xc+=64){
    __syncthreads();
    #pragma unroll
    for(int r=0;r<4;r++){
      int f = t + r*256;
      int sl = f >> 6, xx = f & 63;
      ps[sl][xx] = pr[((size_t)bh*SS + st*16 + sl)*SS + xc + xx];
    }
    __syncthreads();
    for(int xx=0; xx<64; xx+=2){
      u32 w0 = vbase[(size_t)(xc+xx  )*256 + t];
      u32 w1 = vbase[(size_t)(xc+xx+1)*256 + t];
      float v0a = __uint_as_float(w0 << 16);
      float v0b = __uint_as_float(w0 & 0xFFFF0000u);
      float v1a = __uint_as_float(w1 << 16);
      float v1b = __uint_as_float(w1 & 0xFFFF0000u);
      #pragma unroll
      for(int sl=0;sl<16;sl++){
        float2 pp = *(const float2*)&ps[sl][xx];
        acc[sl*2+0] = fmaf(pp.x, v0a, acc[sl*2+0]);
        acc[sl*2+1] = fmaf(pp.x, v0b, acc[sl*2+1]);
        acc[sl*2+0] = fmaf(pp.y, v1a, acc[sl*2+0]);
        acc[sl*2+1] = fmaf(pp.y, v1b, acc[sl*2+1]);
      }
    }
  }

  int b = bh >> 3, h = bh & 7;
  int c0 = t*2; int d = c0 >> 5; int l = c0 & 31;
  u32* om32 = (u32*)om;
  #pragma unroll
  for(int sl=0; sl<16; sl++){
    int s = st*16 + sl;
    u32 pk = (u32)f2bf(acc[sl*2]) | ((u32)f2bf(acc[sl*2+1])<<16);
    om32[(((size_t)(b*SS + s)*128 + h*16 + d)*32 + l) >> 1] = pk;
  }
}

// ---------------- launch ------------------------------------------------------
extern "C" void kernel_launch(void* const* d_in, const int* in_sizes, int n_in,
                              void* d_out, int out_size, void* d_ws, size_t ws_size,
                              hipStream_t stream) {
  const float* x   = (const float*)d_in[0];
  const float* wq  = (const float*)d_in[1];
  const float* wk  = (const float*)d_in[2];
  const float* wv  = (const float*)d_in[3];
  const float* wo  = (const float*)d_in[4];
  const float* lam = (const float*)d_in[5];
  float* out = (float*)d_out;

  char* ws = (char*)d_ws;
  size_t off = 0;
  u16*   wpk2 = (u16*)(ws + off); off += (size_t)4*98304*2;           // 786 KB
  u16*   xg   = (u16*)(ws + off); off += (size_t)32*768*768*2;        // 36 MB
  float* sc   = (float*)xg;            // 9.4 MB overlay (xg dead when sc live)
  u16*   tmp3 = (u16*)(ws + off); off += (size_t)3*32*768*128*2;      // 18.9 MB
  u16*   qhb  = (u16*)(ws + off); off += (size_t)NBH*SS*512*2;        // 6.3 MB
  u16*   khb  = (u16*)(ws + off); off += (size_t)NBH*SS*512*2;
  u16*   vb   = (u16*)(ws + off); off += (size_t)NBH*SS*512*2;
  u16*   om   = (u16*)(ws + off); off += (size_t)BS*128*32*2;

  repack_wb<<<dim3(384,4),256,0,stream>>>(wq, wk, wv, wo, wpk2);
  gather_k<<<384,256,0,stream>>>(x, 0, xg);
  gemm_proj<<<dim3(6,32,3),256,0,stream>>>(xg, wpk2, tmp3);
  norm_split<<<384,256,0,stream>>>(tmp3,                 qhb, 1);
  norm_split<<<384,256,0,stream>>>(tmp3 +   (size_t)32*768*128, khb, 1);
  norm_split<<<384,256,0,stream>>>(tmp3 + (size_t)2*32*768*128, vb,  1);

  scores_mfma<<<dim3(24,24,16),256,0,stream>>>(qhb, khb, sc, lam);
  softmax_k<<<NBH*SS,64,0,stream>>>(sc);
  pv_k<<<dim3(24,16),256,0,stream>>>(sc, vb, om);

  gather_k<<<384,256,0,stream>>>(om, 1, xg);                       // xgo
  gemm_proj<<<dim3(6,32,1),256,0,stream>>>(xg, wpk2 + (size_t)3*98304, tmp3);
  norm_split<<<384,256,0,stream>>>(tmp3, out, 0);
}

// Round 4
// 264.122 us; speedup vs baseline: 4.6978x; 1.2824x over previous
//
#include <hip/hip_runtime.h>
#include <math.h>

// Problem constants
#define BB    2
#define SS    384
#define DD    128
#define NH    8
#define HDIM  16
#define NBH   16      // B*H
#define BS    768     // B*S

typedef unsigned int   u32;
typedef unsigned short u16;
typedef __attribute__((ext_vector_type(8))) short short8;
typedef __attribute__((ext_vector_type(4))) float f32x4;

// ---------------- compile-time Cl(4,1) geometric-product sign table ----------
struct SignTab { float v[32][32]; };
constexpr int popcnt32c(int x){ int c=0; for(int i=0;i<32;i++) c += (x>>i)&1; return c; }
constexpr int signgp_int(int a, int b){
  int swaps=0; int aa=a>>1;
  while(aa){ swaps += popcnt32c(aa & b); aa >>= 1; }
  int s = (swaps & 1) ? -1 : 1;
  if ((a & b) & 16) s = -s;   // e5 (bit 4) squares to -1
  return s;
}
constexpr SignTab make_signs(){
  SignTab t{};
  for(int a=0;a<32;a++) for(int b=0;b<32;b++)
    t.v[a][b] = (float)signgp_int(a,b);
  return t;
}
constexpr SignTab GPS = make_signs();

// Sign-bit XOR masks for scores B fragment, blade c=(w<<3)|u.
struct MaskTab { u32 v[4][8][4][4]; };
constexpr MaskTab mkmask(){
  MaskTab t{};
  for(int w=0;w<4;w++) for(int u=0;u<8;u++) for(int q=0;q<4;q++) for(int r=0;r<4;r++){
    u32 m = 0;
    for(int h=0;h<2;h++){
      int j = 2*r + h;
      int i = (q<<3) | j;
      int c = (w<<3) | u;
      if (signgp_int(i, i^c) < 0) m |= (h ? 0x80000000u : 0x8000u);
    }
    t.v[w][u][q][r] = m;
  }
  return t;
}
constexpr MaskTab MT = mkmask();

__device__ __forceinline__ u16 f2bf(float f){   // round-to-nearest-even
  u32 x = __float_as_uint(f);
  return (u16)((x + 0x7FFFu + ((x>>16)&1u)) >> 16);
}
__device__ __forceinline__ float bf2f(u16 h){
  return __uint_as_float(((u32)h) << 16);
}

// ---------------- weight repack: wpk2[p][o][jp*128+i] = bf16(w_p[o,i,SV[jp]]) -
__global__ __launch_bounds__(256) void repack_wb(const float* __restrict__ wq,
                                                 const float* __restrict__ wk,
                                                 const float* __restrict__ wv,
                                                 const float* __restrict__ wo,
                                                 u16* __restrict__ wpk2){
  int idx = blockIdx.x*256 + threadIdx.x;
  int p = blockIdx.y;
  const float* w = (p==0)?wq:(p==1)?wk:(p==2)?wv:wo;
  int o   = idx / 768;
  int rem = idx - o*768;
  int jp  = rem >> 7;
  int i   = rem & 127;
  const int SV[6] = {0,1,2,4,8,16};
  wpk2[p*98304 + idx] = f2bf(w[(o*128 + i)*32 + SV[jp]]);
}

// ---------------- blade gather: xg[k][bs][jp*128+i] = sign*src[bs,i,SV[jp]^k] -
#define XLS 33
__global__ __launch_bounds__(256) void gather_k(const void* __restrict__ src,
                                                int src_bf16,
                                                u16* __restrict__ xg){
  __shared__ float xl[2*128*XLS];
  int t = threadIdx.x;
  int bs0 = blockIdx.x*2;
  int bsl = t >> 7, i = t & 127;

  float row[32];
  if (src_bf16){
    const uint4* s4 = (const uint4*)((const u16*)src + (((size_t)(bs0+bsl)*128 + i)*32));
    #pragma unroll
    for(int r=0;r<4;r++){
      uint4 v = s4[r];
      u32 ww[4] = {v.x,v.y,v.z,v.w};
      #pragma unroll
      for(int h=0;h<4;h++){
        row[r*8 + 2*h    ] = __uint_as_float(ww[h] << 16);
        row[r*8 + 2*h + 1] = __uint_as_float(ww[h] & 0xFFFF0000u);
      }
    }
  } else {
    const float4* s4 = (const float4*)((const float*)src + (((size_t)(bs0+bsl)*128 + i)*32));
    #pragma unroll
    for(int r=0;r<8;r++){
      float4 v = s4[r];
      row[r*4+0]=v.x; row[r*4+1]=v.y; row[r*4+2]=v.z; row[r*4+3]=v.w;
    }
  }
  float* xrow = xl + bsl*128*XLS + i*XLS;
  #pragma unroll
  for(int l=0;l<32;l++) xrow[l] = row[l];
  __syncthreads();

  const int SV[6] = {0,1,2,4,8,16};
  u32* xg32 = (u32*)xg;
  #pragma unroll 4
  for(int r=0;r<96;r++){
    int wr = t + r*256;
    int k   = wr / 768;
    int rem = wr - k*768;
    int bl  = rem / 384;
    int r2  = rem - bl*384;
    int jp  = r2 >> 6;
    int ip  = r2 & 63;
    int i2  = ip*2;
    int b   = SV[jp] ^ k;
    float sg = GPS.v[SV[jp]][b];
    const float* base = xl + bl*128*XLS;
    float f0 = base[ i2   *XLS + b] * sg;
    float f1 = base[(i2+1)*XLS + b] * sg;
    u32 pk = (u32)f2bf(f0) | ((u32)f2bf(f1) << 16);
    xg32[((size_t)k*768 + bs0 + bl)*384 + jp*64 + ip] = pk;
  }
}

// ---------------- projection GEMM --------------------------------------------
#define LSTR 40
__global__ __launch_bounds__(256) void gemm_proj(const u16* __restrict__ xg,
                                                 const u16* __restrict__ wpkA,
                                                 u16* __restrict__ tmpA){
  __shared__ __align__(16) u16 As[128*LSTR];
  __shared__ __align__(16) u16 Bs[128*LSTR];
  int t = threadIdx.x;
  int Mt = blockIdx.x, k = blockIdx.y, p = blockIdx.z;
  const u16* wpk = wpkA + (size_t)p*98304;
  u16* tmp = tmpA + (size_t)p*32*768*128;

  int w = t >> 6, lane = t & 63;
  int q = lane >> 4, n16 = lane & 15;
  int wm = w >> 1, wn = w & 1;

  f32x4 acc[4][4];
  #pragma unroll
  for(int a=0;a<4;a++)
    #pragma unroll
    for(int b=0;b<4;b++) acc[a][b] = (f32x4){0.f,0.f,0.f,0.f};

  int r0 = t>>2, c0 = (t&3)*8;
  int r1 = (t+256)>>2, c1 = ((t+256)&3)*8;
  const u16* Aab = xg + ((size_t)k*768 + Mt*128)*768;

  uint4 pa0, pa1, pb0, pb1;
  {
    pa0 = *(const uint4*)(Aab + (size_t)r0*768 + c0);
    pa1 = *(const uint4*)(Aab + (size_t)r1*768 + c1);
    pb0 = *(const uint4*)(wpk + (size_t)r0*768 + c0);
    pb1 = *(const uint4*)(wpk + (size_t)r1*768 + c1);
  }

  for(int kt=0; kt<24; kt++){
    __syncthreads();
    *(uint4*)(As + r0*LSTR + c0) = pa0;
    *(uint4*)(As + r1*LSTR + c1) = pa1;
    *(uint4*)(Bs + r0*LSTR + c0) = pb0;
    *(uint4*)(Bs + r1*LSTR + c1) = pb1;
    __syncthreads();
    if (kt < 23){
      int kn = (kt+1)*32;
      pa0 = *(const uint4*)(Aab + (size_t)r0*768 + kn + c0);
      pa1 = *(const uint4*)(Aab + (size_t)r1*768 + kn + c1);
      pb0 = *(const uint4*)(wpk + (size_t)r0*768 + kn + c0);
      pb1 = *(const uint4*)(wpk + (size_t)r1*768 + kn + c1);
    }
    short8 a[4], b[4];
    #pragma unroll
    for(int mi=0;mi<4;mi++)
      a[mi] = *(const short8*)(As + (wm*64 + mi*16 + n16)*LSTR + q*8);
    #pragma unroll
    for(int ni=0;ni<4;ni++)
      b[ni] = *(const short8*)(Bs + (wn*64 + ni*16 + n16)*LSTR + q*8);
    #pragma unroll
    for(int mi=0;mi<4;mi++)
      #pragma unroll
      for(int ni=0;ni<4;ni++)
        acc[mi][ni] = __builtin_amdgcn_mfma_f32_16x16x32_bf16(a[mi], b[ni], acc[mi][ni], 0,0,0);
  }

  #pragma unroll
  for(int mi=0;mi<4;mi++){
    #pragma unroll
    for(int r=0;r<4;r++){
      int m = Mt*128 + wm*64 + mi*16 + q*4 + r;
      #pragma unroll
      for(int ni=0;ni<4;ni++){
        int n = wn*64 + ni*16 + n16;
        tmp[((size_t)k*768 + m)*128 + n] = f2bf(acc[mi][ni][r]);
      }
    }
  }
}

// ---------------- normalize + head-split for Q,K,V (one dispatch) ------------
__global__ __launch_bounds__(256) void norm3(const u16* __restrict__ tmpA,
                                             u16* __restrict__ qhb,
                                             u16* __restrict__ khb,
                                             u16* __restrict__ vbb){
  int z = blockIdx.y;
  const u16* tmp = tmpA + (size_t)z*32*768*128;
  u16* dst = (z==0)?qhb:(z==1)?khb:vbb;
  int t = threadIdx.x;
  int bsl = t >> 7, o = t & 127;
  int bs = blockIdx.x*2 + bsl;

  float a[32];
  float ssum = 1e-8f;
  #pragma unroll
  for(int k=0;k<32;k++){
    a[k] = bf2f(tmp[((size_t)k*768 + bs)*128 + o]);
    ssum = fmaf(a[k], a[k], ssum);
  }
  float inv = 1.0f / sqrtf(ssum);

  int b = bs / SS, s = bs - b*SS;
  int h = o >> 4, d = o & 15;
  uint4* og4 = (uint4*)(dst + (((size_t)(b*NH + h)*SS + s)*512 + d*32));
  #pragma unroll
  for(int l=0;l<4;l++){
    uint4 v;
    v.x = (u32)f2bf(a[8*l+0]*inv) | ((u32)f2bf(a[8*l+1]*inv)<<16);
    v.y = (u32)f2bf(a[8*l+2]*inv) | ((u32)f2bf(a[8*l+3]*inv)<<16);
    v.z = (u32)f2bf(a[8*l+4]*inv) | ((u32)f2bf(a[8*l+5]*inv)<<16);
    v.w = (u32)f2bf(a[8*l+6]*inv) | ((u32)f2bf(a[8*l+7]*inv)<<16);
    og4[l] = v;
  }
}

// ---------------- normalize, fp32 flat out (output projection) ---------------
__global__ __launch_bounds__(256) void norm_out(const u16* __restrict__ tmp,
                                                float* __restrict__ dst){
  int t = threadIdx.x;
  int bsl = t >> 7, o = t & 127;
  int bs = blockIdx.x*2 + bsl;

  float a[32];
  float ssum = 1e-8f;
  #pragma unroll
  for(int k=0;k<32;k++){
    a[k] = bf2f(tmp[((size_t)k*768 + bs)*128 + o]);
    ssum = fmaf(a[k], a[k], ssum);
  }
  float inv = 1.0f / sqrtf(ssum);
  float4* og = (float4*)(dst + ((size_t)bs*128 + o)*32);
  #pragma unroll
  for(int l4=0;l4<8;l4++){
    float4 v;
    v.x = a[4*l4+0]*inv; v.y = a[4*l4+1]*inv;
    v.z = a[4*l4+2]*inv; v.w = a[4*l4+3]*inv;
    og[l4] = v;
  }
}

// ---------------- V transpose: vt[bh][dl][x] = vb[bh][x][dl] -----------------
#define TVS 528
__global__ __launch_bounds__(256) void transpose_v(const u16* __restrict__ vb,
                                                   u16* __restrict__ vt){
  __shared__ __align__(16) u16 vl[32*TVS];
  int t = threadIdx.x;
  int xt = blockIdx.x, bh = blockIdx.y;   // xt<12
  const u16* src = vb + ((size_t)bh*SS + xt*32)*512;
  #pragma unroll
  for(int j=0;j<8;j++){
    int f = t + j*256; int row = f>>6, c = (f&63)*8;
    *(uint4*)(vl + row*TVS + c) = *(const uint4*)(src + (size_t)row*512 + c);
  }
  __syncthreads();
  u16* dst = vt + (size_t)bh*512*SS + xt*32;
  #pragma unroll
  for(int j=0;j<8;j++){
    int f = t + j*256; int dl = f>>2, c4 = (f&3)*8;
    u16 tmp[8];
    #pragma unroll
    for(int e=0;e<8;e++) tmp[e] = vl[(c4+e)*TVS + dl];
    *(uint4*)(dst + (size_t)dl*SS + c4) = *(uint4*)tmp;
  }
}

// ---------------- MFMA attention scores, 64-row tiles ------------------------
// Block: 64 s x 16 x; wave w: blades c=w*8+u for all 64 s (4 A-frags per B).
#define QSTR 264   // LDS row stride in u16 (528 B = 33x16, bank-stride 4)
__global__ __launch_bounds__(256,2) void scores_mfma(const u16* __restrict__ qh,
                                                     const u16* __restrict__ kh,
                                                     float* __restrict__ sc,
                                                     const float* __restrict__ lam){
  __shared__ __align__(16) u16 smem[(64+16)*QSTR];   // 42.24 KB
  u16* qs = smem;
  u16* ks = smem + 64*QSTR;
  int t = threadIdx.x;
  int xt = blockIdx.x, st = blockIdx.y, bh = blockIdx.z;
  int w = t >> 6, lane = t & 63, q = lane >> 4, mn = lane & 15;

  u32 FM[8][4];
  #pragma unroll
  for(int u=0;u<8;u++)
    #pragma unroll
    for(int r=0;r<4;r++) FM[u][r] = MT.v[w][u][q][r];

  f32x4 acc[4][8];
  #pragma unroll
  for(int mi=0;mi<4;mi++)
    #pragma unroll
    for(int u=0;u<8;u++) acc[mi][u] = (f32x4){0.f,0.f,0.f,0.f};

  for(int h=0; h<2; h++){
    __syncthreads();
    const u16* qbase = qh + ((size_t)bh*SS + st*64)*512 + h*256;
    const u16* kbase = kh + ((size_t)bh*SS + xt*16)*512 + h*256;
    #pragma unroll
    for(int j=0;j<8;j++){
      int f = t + j*256;
      int row = f>>5, c = (f&31)*8;
      *(uint4*)(qs + row*QSTR + c) = *(const uint4*)(qbase + (size_t)row*512 + c);
    }
    #pragma unroll
    for(int j=0;j<2;j++){
      int f = t + j*256;
      int row = f>>5, c = (f&31)*8;
      *(uint4*)(ks + row*QSTR + c) = *(const uint4*)(kbase + (size_t)row*512 + c);
    }
    __syncthreads();

    for(int ktl=0; ktl<8; ktl++){
      short8 a[4];
      #pragma unroll
      for(int mi=0;mi<4;mi++)
        a[mi] = *(const short8*)(qs + (mi*16+mn)*QSTR + ktl*32 + q*8);
      uint4 khd = *(const uint4*)(ks + mn*QSTR + ktl*32 + ((q^w)<<3));
      u32 kk[4] = {khd.x, khd.y, khd.z, khd.w};
      #pragma unroll
      for(int u=0;u<8;u++){
        union { u32 w32[4]; short8 s; } bf;
        #pragma unroll
        for(int r=0;r<4;r++){
          u32 v = kk[r ^ (u>>1)];
          if (u & 1) v = (v>>16)|(v<<16);
          bf.w32[r] = v ^ FM[u][r];
        }
        #pragma unroll
        for(int mi=0;mi<4;mi++)
          acc[mi][u] = __builtin_amdgcn_mfma_f32_16x16x32_bf16(a[mi], bf.s, acc[mi][u], 0, 0, 0);
      }
    }
  }
  __syncthreads();

  float* pss = (float*)smem;          // [4][64][17] = 17408 B
  float* pbb = pss + 4*64*17;         // [4][64][17]
  float* ps0 = pbb + 4*64*17;         // [64][17]

  #pragma unroll
  for(int mi=0;mi<4;mi++){
    #pragma unroll
    for(int rr=0;rr<4;rr++){
      float ssv = 0.f, bbv = 0.f;
      #pragma unroll
      for(int u=0;u<8;u++){
        int c = w*8 + u;
        bool isb = (c==3)||(c==5)||(c==6)||(c==9)||(c==10)||(c==12)||
                   (c==17)||(c==18)||(c==20)||(c==24);
        float v = acc[mi][u][rr];
        ssv = fmaf(v, v, ssv);
        if (isb) bbv = fmaf(v, v, bbv);
      }
      int s = mi*16 + q*4 + rr;
      pss[(w*64 + s)*17 + mn] = ssv;
      pbb[(w*64 + s)*17 + mn] = bbv;
      if (w == 0) ps0[s*17 + mn] = acc[mi][0][rr];
    }
  }
  __syncthreads();

  int x = t & 15, s0 = t >> 4;
  float lm = lam[0];
  #pragma unroll
  for(int ssi=0; ssi<4; ssi++){
    int s = s0 + ssi*16;
    float ss = 1e-8f, bb = 0.f;
    #pragma unroll
    for(int ww=0; ww<4; ww++){
      ss += pss[(ww*64+s)*17+x];
      bb += pbb[(ww*64+s)*17+x];
    }
    float inv = 1.0f / sqrtf(ss);
    float s0v = ps0[s*17+x];
    float score = (s0v*inv + lm*sqrtf(bb*inv*inv + 1e-8f)) * 0.25f;
    sc[((size_t)bh*SS + st*64 + s)*SS + xt*16 + x] = score;
  }
}

// ---------------- fused softmax + P@V (MFMA) ---------------------------------
// Block (st 0..23, bh): softmax over 16 score rows -> P bf16 in LDS;
// OT[dl][s] = sum_x Vt[dl][x] * P[s][x] via mfma (A=Vt chunk, B=P);
// epilogue repacks to om natural (bs,128,32) bf16.
#define PBS 392   // P LDS row stride u16
#define VSS 40    // Vt chunk LDS row stride u16
__global__ __launch_bounds__(256,2) void pv_mfma(const float* __restrict__ sc,
                                                 const u16* __restrict__ vt,
                                                 u16* __restrict__ om){
  __shared__ __align__(16) u16 pb[16*PBS];
  __shared__ __align__(16) u16 vsm[512*VSS];       // overlaid by ot[512][17] f32
  int t = threadIdx.x;
  int st = blockIdx.x, bh = blockIdx.y;
  int w = t >> 6, lane = t & 63, q = lane >> 4, mn = lane & 15;

  { // softmax prologue: row = t>>4 handled by 16-lane group
    int row = t >> 4, g = t & 15;
    const float* srow = sc + ((size_t)bh*SS + st*16 + row)*SS;
    float v[24];
    float mx = -1e30f;
    #pragma unroll
    for(int k2=0;k2<24;k2++){ v[k2] = srow[g + k2*16]; mx = fmaxf(mx, v[k2]); }
    #pragma unroll
    for(int off=8; off; off>>=1) mx = fmaxf(mx, __shfl_xor(mx, off));
    float sum = 0.f;
    #pragma unroll
    for(int k2=0;k2<24;k2++){ v[k2] = __expf(v[k2]-mx); sum += v[k2]; }
    #pragma unroll
    for(int off=8; off; off>>=1) sum += __shfl_xor(sum, off);
    float inv = 1.f/sum;
    #pragma unroll
    for(int k2=0;k2<24;k2++) pb[row*PBS + g + k2*16] = f2bf(v[k2]*inv);
  }

  f32x4 acc[8];
  #pragma unroll
  for(int mt=0;mt<8;mt++) acc[mt] = (f32x4){0.f,0.f,0.f,0.f};

  const u16* vtb = vt + (size_t)bh*512*SS;
  for(int kt=0; kt<12; kt++){
    __syncthreads();
    #pragma unroll
    for(int j=0;j<8;j++){
      int f = t + j*256;
      int dl = f>>2, c4 = (f&3)*8;
      *(uint4*)(vsm + dl*VSS + c4) = *(const uint4*)(vtb + (size_t)dl*SS + kt*32 + c4);
    }
    __syncthreads();
    short8 b = *(const short8*)(pb + mn*PBS + kt*32 + q*8);
    #pragma unroll
    for(int mt=0;mt<8;mt++){
      short8 a = *(const short8*)(vsm + ((w*8+mt)*16 + mn)*VSS + q*8);
      acc[mt] = __builtin_amdgcn_mfma_f32_16x16x32_bf16(a, b, acc[mt], 0, 0, 0);
    }
  }
  __syncthreads();

  float* ot = (float*)vsm;    // [512][17] = 34.8 KB
  #pragma unroll
  for(int mt=0;mt<8;mt++)
    #pragma unroll
    for(int rr=0;rr<4;rr++)
      ot[((w*8+mt)*16 + q*4 + rr)*17 + mn] = acc[mt][rr];
  __syncthreads();

  int b = bh >> 3, h = bh & 7;
  u32* om32 = (u32*)om;
  #pragma unroll
  for(int j=0;j<16;j++){
    int f = t + j*256;          // 4096 u32 = 16 s x 256 dl-pairs
    int s = f >> 8, dlp = f & 255, dl = dlp*2;
    float f0 = ot[dl*17 + s], f1 = ot[(dl+1)*17 + s];
    u32 pk = (u32)f2bf(f0) | ((u32)f2bf(f1) << 16);
    int sg = st*16 + s;
    om32[(size_t)(b*SS + sg)*2048 + h*256 + dlp] = pk;
  }
}

// ---------------- launch ------------------------------------------------------
extern "C" void kernel_launch(void* const* d_in, const int* in_sizes, int n_in,
                              void* d_out, int out_size, void* d_ws, size_t ws_size,
                              hipStream_t stream) {
  const float* x   = (const float*)d_in[0];
  const float* wq  = (const float*)d_in[1];
  const float* wk  = (const float*)d_in[2];
  const float* wv  = (const float*)d_in[3];
  const float* wo  = (const float*)d_in[4];
  const float* lam = (const float*)d_in[5];
  float* out = (float*)d_out;

  char* ws = (char*)d_ws;
  size_t off = 0;
  u16*   wpk2 = (u16*)(ws + off); off += (size_t)4*98304*2;
  u16*   xg   = (u16*)(ws + off); off += (size_t)32*768*768*2;        // 36 MB
  float* sc   = (float*)xg;            // 9.4 MB overlay (xg dead when sc live)
  u16*   tmp3 = (u16*)(ws + off); off += (size_t)3*32*768*128*2;      // 18.9 MB
  u16*   vt   = tmp3;                  // 6.3 MB overlay (tmp3 dead after norm3)
  u16*   qhb  = (u16*)(ws + off); off += (size_t)NBH*SS*512*2;
  u16*   khb  = (u16*)(ws + off); off += (size_t)NBH*SS*512*2;
  u16*   vb   = (u16*)(ws + off); off += (size_t)NBH*SS*512*2;
  u16*   om   = (u16*)(ws + off); off += (size_t)BS*128*32*2;

  repack_wb<<<dim3(384,4),256,0,stream>>>(wq, wk, wv, wo, wpk2);
  gather_k<<<384,256,0,stream>>>(x, 0, xg);
  gemm_proj<<<dim3(6,32,3),256,0,stream>>>(xg, wpk2, tmp3);
  norm3<<<dim3(384,3),256,0,stream>>>(tmp3, qhb, khb, vb);
  transpose_v<<<dim3(12,16),256,0,stream>>>(vb, vt);

  scores_mfma<<<dim3(24,6,16),256,0,stream>>>(qhb, khb, sc, lam);
  pv_mfma<<<dim3(24,16),256,0,stream>>>(sc, vt, om);

  gather_k<<<384,256,0,stream>>>(om, 1, xg);
  gemm_proj<<<dim3(6,32,1),256,0,stream>>>(xg, wpk2 + (size_t)3*98304, tmp3);
  norm_out<<<384,256,0,stream>>>(tmp3, out);
}